// Round 5
// baseline (1055.702 us; speedup 1.0000x reference)
//
#include <hip/hip_runtime.h>
#include <hip/hip_fp16.h>

typedef float    f32x4 __attribute__((ext_vector_type(4)));
typedef _Float16 f16x8 __attribute__((ext_vector_type(8)));
typedef _Float16 f16x4 __attribute__((ext_vector_type(4)));

__device__ __forceinline__ float sigmoidf_(float x) { return 1.f / (1.f + __expf(-x)); }
__device__ __forceinline__ float tanhf_(float x) { float e = __expf(2.f * x); return 1.f - 2.f / (e + 1.f); }
__device__ __forceinline__ float lrelu_(float v) { return v > 0.f ? v : 0.01f * v; }

__device__ __forceinline__ f16x8 cvt8(const float* p) {
    const f32x4* q = (const f32x4*)p;
    f32x4 a = q[0], b = q[1];
    f16x8 v;
    v[0] = (_Float16)a[0]; v[1] = (_Float16)a[1]; v[2] = (_Float16)a[2]; v[3] = (_Float16)a[3];
    v[4] = (_Float16)b[0]; v[5] = (_Float16)b[1]; v[6] = (_Float16)b[2]; v[7] = (_Float16)b[3];
    return v;
}

// ---------------- LayerNorm + cast to f16, row-major [NT][128] ----------------
__global__ __launch_bounds__(256) void k_ln(const float* __restrict__ x,
                                            const float* __restrict__ g,
                                            const float* __restrict__ b,
                                            _Float16* __restrict__ xn)
{
    int tid = threadIdx.x;
    int r = tid >> 4, i = tid & 15;
    size_t row = (size_t)blockIdx.x * 16 + r;
    const f32x4* xp = (const f32x4*)(x + row * 128 + i * 8);
    f32x4 a0 = xp[0], a1 = xp[1];
    float v0=a0[0], v1=a0[1], v2=a0[2], v3=a0[3], v4=a1[0], v5=a1[1], v6=a1[2], v7=a1[3];
    float s  = v0+v1+v2+v3+v4+v5+v6+v7;
    float s2 = v0*v0+v1*v1+v2*v2+v3*v3+v4*v4+v5*v5+v6*v6+v7*v7;
#pragma unroll
    for (int m = 1; m <= 8; m <<= 1) { s += __shfl_xor(s, m); s2 += __shfl_xor(s2, m); }
    float mu  = s * (1.f / 128.f);
    float var = s2 * (1.f / 128.f) - mu * mu;
    float rs  = rsqrtf(var + 1e-5f);
    const f32x4* gp = (const f32x4*)(g + i * 8);
    const f32x4* bp = (const f32x4*)(b + i * 8);
    f32x4 g0 = gp[0], g1 = gp[1], bb0 = bp[0], bb1 = bp[1];
    f16x8 o;
    o[0] = (_Float16)((v0 - mu) * rs * g0[0] + bb0[0]);
    o[1] = (_Float16)((v1 - mu) * rs * g0[1] + bb0[1]);
    o[2] = (_Float16)((v2 - mu) * rs * g0[2] + bb0[2]);
    o[3] = (_Float16)((v3 - mu) * rs * g0[3] + bb0[3]);
    o[4] = (_Float16)((v4 - mu) * rs * g1[0] + bb1[0]);
    o[5] = (_Float16)((v5 - mu) * rs * g1[1] + bb1[1]);
    o[6] = (_Float16)((v6 - mu) * rs * g1[2] + bb1[2]);
    o[7] = (_Float16)((v7 - mu) * rs * g1[3] + bb1[3]);
    *(f16x8*)(xn + row * 128 + i * 8) = o;
}

// ---------------- xg = xin @ W_ih^T, stored PRE-PERMUTED for k_gru ----------------
// Block owns 8 batch rows (MFMA rows 8-15 dup 0-7). Lane (w,ul,q) computes gate
// cols u=w*16+ul (+g*128) for C rows q*4+j. Only q<2 lanes (real rows) store:
//   slot = (blk*64+t)*256 + w*32 + q*16 + ul
//   xgA[slot] = {r0..r3, z0..z3} (f16x8, 16B)   xgB[slot] = {n0..n3} (f16x4, 8B)
__global__ __launch_bounds__(512, 4) void k_xg(const _Float16* __restrict__ xin,
                                               const float* __restrict__ W,
                                               _Float16* __restrict__ xgA,
                                               _Float16* __restrict__ xgB)
{
    int tid = threadIdx.x;
    int w = tid >> 6, lane = tid & 63;
    int ul = lane & 15, q = lane >> 4;
    int u = w * 16 + ul;
    f16x8 wf[12];
#pragma unroll
    for (int g = 0; g < 3; ++g)
#pragma unroll
        for (int kt = 0; kt < 4; ++kt)
            wf[g * 4 + kt] = cvt8(W + (size_t)(u + g * 128) * 128 + kt * 32 + q * 8);
    int n0 = blockIdx.x * 8;
    const _Float16* xr = xin + ((size_t)(n0 + (ul & 7)) * 64) * 128 + q * 8;
    size_t slot0 = (size_t)blockIdx.x * 64 * 256 + (w * 32 + (q & 1) * 16 + ul);
    const f32x4 zero4 = {0.f, 0.f, 0.f, 0.f};
    for (int t = 0; t < 64; ++t) {
        f16x8 xf[4];
#pragma unroll
        for (int kt = 0; kt < 4; ++kt) xf[kt] = *(const f16x8*)(xr + kt * 32);
        xr += 128;
        f32x4 ac[3];
#pragma unroll
        for (int g = 0; g < 3; ++g) ac[g] = zero4;
#pragma unroll
        for (int g = 0; g < 3; ++g)
#pragma unroll
            for (int kt = 0; kt < 4; ++kt)
                ac[g] = __builtin_amdgcn_mfma_f32_16x16x32_f16(xf[kt], wf[g * 4 + kt], ac[g], 0, 0, 0);
        if (q < 2) {
            size_t slot = slot0 + (size_t)t * 256;
            f16x8 va; f16x4 vb;
#pragma unroll
            for (int j = 0; j < 4; ++j) {
                va[j]     = (_Float16)ac[0][j];
                va[4 + j] = (_Float16)ac[1][j];
                vb[j]     = (_Float16)ac[2][j];
            }
            *(f16x8*)(xgA + slot * 8) = va;
            *(f16x4*)(xgB + slot * 4) = vb;
        }
    }
}

// ---------------- Recurrent GRU: compact pre-permuted xg; W_hh in regs --------------
__global__ __launch_bounds__(512, 4) void k_gru(const _Float16* __restrict__ xgA,
                                                const _Float16* __restrict__ xgB,
                                                const float* __restrict__ W_hh,
                                                const float* __restrict__ b_ih,
                                                const float* __restrict__ b_hh,
                                                _Float16* __restrict__ hout,
                                                float* __restrict__ es)
{
    __shared__ __align__(16) _Float16 hbuf[2][16 * 136];
    int tid = threadIdx.x;
    int w = tid >> 6, lane = tid & 63;
    int ul = lane & 15, q = lane >> 4;
    int u = w * 16 + ul;
    int n0 = blockIdx.x * 8;

    f16x8 whh[12];
#pragma unroll
    for (int g = 0; g < 3; ++g)
#pragma unroll
        for (int kt = 0; kt < 4; ++kt)
            whh[g * 4 + kt] = cvt8(W_hh + (size_t)(u + g * 128) * 128 + kt * 32 + q * 8);
    float br = b_ih[u] + b_hh[u];
    float bz = b_ih[u + 128] + b_hh[u + 128];
    float bi2 = b_ih[u + 256], bh2 = b_hh[u + 256];

    size_t slot0 = (size_t)blockIdx.x * 64 * 256 + (w * 32 + (q & 1) * 16 + ul);
    const f16x8* pA = (const f16x8*)xgA;
    const f16x4* pB = (const f16x4*)xgB;
    f16x8 curA = pA[slot0];
    f16x4 curB = pB[slot0];

    for (int idx = tid; idx < 16 * 136; idx += 512) hbuf[0][idx] = (_Float16)0.f;
    float hh[4] = {0.f, 0.f, 0.f, 0.f};
    __syncthreads();

    int p = 0;
    const f32x4 zero4 = {0.f, 0.f, 0.f, 0.f};
    for (int t = 0; t < 64; ++t) {
        size_t sn = slot0 + (size_t)((t < 63) ? (t + 1) : t) * 256;
        f16x8 nxtA = pA[sn];
        f16x4 nxtB = pB[sn];

        f16x8 hf[4];
        const _Float16* hb = &hbuf[p][ul * 136 + q * 8];
#pragma unroll
        for (int kt = 0; kt < 4; ++kt) hf[kt] = *(const f16x8*)(hb + kt * 32);

        f32x4 ah[3];
#pragma unroll
        for (int g = 0; g < 3; ++g) ah[g] = zero4;
#pragma unroll
        for (int g = 0; g < 3; ++g)
#pragma unroll
            for (int kt = 0; kt < 4; ++kt)
                ah[g] = __builtin_amdgcn_mfma_f32_16x16x32_f16(hf[kt], whh[g * 4 + kt], ah[g], 0, 0, 0);

        _Float16* wb = &hbuf[p ^ 1][0];
#pragma unroll
        for (int j = 0; j < 4; ++j) {
            float rr = sigmoidf_((float)curA[j] + ah[0][j] + br);
            float zz = sigmoidf_((float)curA[4 + j] + ah[1][j] + bz);
            float nn = tanhf_((float)curB[j] + bi2 + rr * (ah[2][j] + bh2));
            float hn = (1.f - zz) * nn + zz * hh[j];
            hh[j] = hn;
            wb[(q * 4 + j) * 136 + u] = (_Float16)hn;
        }
        __syncthreads();
        p ^= 1;
        if (hout != nullptr && tid < 128) {
            int r2 = tid >> 4, seg = tid & 15;
            f16x8 v = *(const f16x8*)&hbuf[p][r2 * 136 + seg * 8];
            *(f16x8*)(hout + ((size_t)(n0 + r2) * 64 + t) * 128 + seg * 8) = v;
        }
        curA = nxtA; curB = nxtB;
    }
    if (es != nullptr && q < 2) {
#pragma unroll
        for (int j = 0; j < 4; ++j)
            es[(size_t)(n0 + q * 4 + j) * 128 + u] = hh[j];
    }
}

// ---------------- beta = sigmoid(A @ prot^T), rowsum -> dn ----------------
__global__ __launch_bounds__(256) void k_mm32(const float* __restrict__ A,
                                              const float* __restrict__ W,
                                              float* __restrict__ out,
                                              float* __restrict__ rowsum)
{
    __shared__ __align__(16) _Float16 Wls[32 * 136];
    int tid = threadIdx.x;
    for (int idx = tid; idx < 32 * 128; idx += 256) {
        int o = idx >> 7, k = idx & 127;
        Wls[o * 136 + k] = (_Float16)W[idx];
    }
    __syncthreads();
    int o = tid & 31, r = tid >> 5;
    size_t n = (size_t)blockIdx.x * 8 + r;
    const f32x4* Ap = (const f32x4*)(A + n * 128);
    float acc = 0.f;
#pragma unroll 4
    for (int k8 = 0; k8 < 16; ++k8) {
        f16x8 wv = *(const f16x8*)&Wls[o * 136 + k8 * 8];
        f32x4 a0 = Ap[k8 * 2], a1 = Ap[k8 * 2 + 1];
        acc += (float)wv[0] * a0[0] + (float)wv[1] * a0[1] + (float)wv[2] * a0[2] + (float)wv[3] * a0[3]
             + (float)wv[4] * a1[0] + (float)wv[5] * a1[1] + (float)wv[6] * a1[2] + (float)wv[7] * a1[3];
    }
    float v = sigmoidf_(acc);
    out[n * 32 + o] = v;
    float s = v;
#pragma unroll
    for (int m = 1; m < 32; m <<= 1) s += __shfl_xor(s, m);
    if (o == 0) rowsum[n] = s;
}

// ---------------- edge reduce, stage 1: G[j][c] partials = sum_n S[n][j]*X[n][c] ----
__global__ __launch_bounds__(256) void k_edge_part(const void* __restrict__ S, int isInt,
                                                   const float* __restrict__ X,
                                                   float* __restrict__ part,
                                                   float* __restrict__ d_e,
                                                   int E, int N, int rowsPerBlk)
{
    int tid = threadIdx.x;
    int pair = tid >> 7, c = tid & 127, lane = tid & 63;
    int JG = E >> 5;
    int jg, rOff, rStep;
    if (JG == 2) { jg = pair; rOff = 0; rStep = 1; }
    else         { jg = 0;    rOff = pair; rStep = 2; }
    int n0 = blockIdx.x * rowsPerBlk;
    int n1 = n0 + rowsPerBlk; if (n1 > N) n1 = N;
    const int* Si = (const int*)S; const float* Sf = (const float*)S;
    int js = jg * 32 + (lane & 31);

    float acc[32];
#pragma unroll
    for (int i = 0; i < 32; ++i) acc[i] = 0.f;
    float dcnt = 0.f;

    for (int n = n0 + rOff; n < n1; n += rStep) {
        float sval = isInt ? (float)Si[(size_t)n * E + js] : Sf[(size_t)n * E + js];
        float xc = X[(size_t)n * 128 + c];
        dcnt += sval;
        int sv = __float_as_int(sval);
#pragma unroll
        for (int jj = 0; jj < 32; ++jj) {
            float s = __int_as_float(__builtin_amdgcn_readlane(sv, jj));
            acc[jj] += s * xc;
        }
    }
    float* pp = part + ((size_t)(blockIdx.x * 2 + pair) * 32) * 128;
#pragma unroll
    for (int jj = 0; jj < 32; ++jj)
        pp[(size_t)jj * 128 + c] = acc[jj];
    int w = tid >> 6;
    if ((w & 1) == 0 && (lane & 32) == 0)
        atomicAdd(&d_e[jg * 32 + lane], dcnt);
}

// ---------------- stage 2: Gsum -> m[j] = (G[j]*scale_j) @ W^T + bias ----------------
__global__ __launch_bounds__(128) void k_finish_mm(const float* __restrict__ part,
                                                   const float* __restrict__ d_e,
                                                   const float* __restrict__ W,
                                                   const float* __restrict__ bias,
                                                   float* __restrict__ m, int P, int JG)
{
    __shared__ __align__(16) float Gj[128];
    int j = blockIdx.x, c = threadIdx.x;
    float acc = 0.f;
    if (JG == 2) {
        int pair = j >> 5, jj = j & 31;
        for (int b = 0; b < P; ++b)
            acc += part[((size_t)(b * 2 + pair) * 32 + jj) * 128 + c];
    } else {
        for (int b = 0; b < 2 * P; ++b)
            acc += part[((size_t)b * 32 + j) * 128 + c];
    }
    float d = d_e[j];
    float s = d > 0.f ? 1.f / d : 0.f;
    Gj[c] = acc * s;
    __syncthreads();
    const f32x4* Wr = (const f32x4*)(W + (size_t)c * 128);
    const f32x4* Gp = (const f32x4*)Gj;
    float dot = 0.f;
#pragma unroll 8
    for (int k4 = 0; k4 < 32; ++k4) {
        f32x4 wv = Wr[k4], gv = Gp[k4];
        dot += wv[0] * gv[0] + wv[1] * gv[1] + wv[2] * gv[2] + wv[3] * gv[3];
    }
    m[j * 128 + c] = dot + (bias ? bias[c] : 0.f);
}

// ---------------- hconv apply: 8 rows/block, m staged once ----------------
__global__ __launch_bounds__(256) void k_hconv_apply(const void* __restrict__ S, int isInt, int E,
                                                     const float* __restrict__ m,
                                                     const float* __restrict__ dn_pre, int sqrtMode,
                                                     const float* __restrict__ bias,
                                                     const float* __restrict__ base,
                                                     float* __restrict__ outMain,
                                                     float* __restrict__ outSub)
{
    __shared__ float mls[64 * 128];
    int tid = threadIdx.x;
    for (int idx = tid; idx < E * 128; idx += 256) mls[idx] = m[idx];
    __syncthreads();
    int c = tid & 127, r = tid >> 7;
    for (int pass = 0; pass < 4; ++pass) {
        size_t n = (size_t)blockIdx.x * 8 + pass * 2 + r;
        float acc = 0.f, d = 0.f;
        if (isInt) {
            const int4* Sr = (const int4*)((const int*)S + n * E);
            for (int jg = 0; jg < E / 4; ++jg) {
                int4 s4 = Sr[jg];
                acc += (float)s4.x * mls[(jg * 4 + 0) * 128 + c]
                     + (float)s4.y * mls[(jg * 4 + 1) * 128 + c]
                     + (float)s4.z * mls[(jg * 4 + 2) * 128 + c]
                     + (float)s4.w * mls[(jg * 4 + 3) * 128 + c];
                d += (float)(s4.x + s4.y + s4.z + s4.w);
            }
        } else {
            const f32x4* Sr = (const f32x4*)((const float*)S + n * E);
            for (int jg = 0; jg < E / 4; ++jg) {
                f32x4 s4 = Sr[jg];
                acc += s4[0] * mls[(jg * 4 + 0) * 128 + c]
                     + s4[1] * mls[(jg * 4 + 1) * 128 + c]
                     + s4[2] * mls[(jg * 4 + 2) * 128 + c]
                     + s4[3] * mls[(jg * 4 + 3) * 128 + c];
                d += s4[0] + s4[1] + s4[2] + s4[3];
            }
        }
        if (dn_pre) d = dn_pre[n];
        float sc = d > 0.f ? (sqrtMode ? rsqrtf(d) : 1.f / d) : 0.f;
        float v = acc * sc + (bias ? bias[c] : 0.f);
        v = lrelu_(v);
        outMain[n * 128 + c] = v;
        if (outSub) outSub[n * 128 + c] = base[n * 128 + c] - v;
    }
}

// ---------------- tail: e_al = lrelu(e_res@Wa^T+ba); out = [e_p|e_h|e_al].Wf + bf ----
__global__ __launch_bounds__(512) void k_tail(const float* __restrict__ e_res,
                                              const float* __restrict__ Wa,
                                              const float* __restrict__ ba,
                                              const float* __restrict__ ep,
                                              const float* __restrict__ eh,
                                              const float* __restrict__ Wf,
                                              const float* __restrict__ bf,
                                              float* __restrict__ out)
{
    __shared__ __align__(16) _Float16 Wls[128 * 136];
    __shared__ float wfl[384];
    __shared__ float sred[8];
    int tid = threadIdx.x;
    for (int idx = tid; idx < 128 * 128; idx += 512) {
        int o = idx >> 7, k = idx & 127;
        Wls[o * 136 + k] = (_Float16)Wa[idx];
    }
    for (int idx = tid; idx < 384; idx += 512) wfl[idx] = Wf[idx];
    __syncthreads();
    int o = tid & 127, r = tid >> 7;
    for (int pass = 0; pass < 4; ++pass) {
        size_t n = (size_t)blockIdx.x * 16 + pass * 4 + r;
        const f32x4* Ap = (const f32x4*)(e_res + n * 128);
        float acc = ba[o];
#pragma unroll 4
        for (int k8 = 0; k8 < 16; ++k8) {
            f16x8 wv = *(const f16x8*)&Wls[o * 136 + k8 * 8];
            f32x4 a0 = Ap[k8 * 2], a1 = Ap[k8 * 2 + 1];
            acc += (float)wv[0] * a0[0] + (float)wv[1] * a0[1] + (float)wv[2] * a0[2] + (float)wv[3] * a0[3]
                 + (float)wv[4] * a1[0] + (float)wv[5] * a1[1] + (float)wv[6] * a1[2] + (float)wv[7] * a1[3];
        }
        float v = lrelu_(acc);
        float term = ep[n * 128 + o] * wfl[o] + eh[n * 128 + o] * wfl[128 + o] + v * wfl[256 + o];
#pragma unroll
        for (int m2 = 1; m2 < 64; m2 <<= 1) term += __shfl_xor(term, m2);
        int wv2 = tid >> 6;
        if ((tid & 63) == 0) sred[wv2] = term;
        __syncthreads();
        if (tid < 4) out[blockIdx.x * 16 + pass * 4 + tid] = sred[2 * tid] + sred[2 * tid + 1] + bf[0];
        __syncthreads();
    }
}

extern "C" void kernel_launch(void* const* d_in, const int* in_sizes, int n_in,
                              void* d_out, int out_size, void* d_ws, size_t ws_size,
                              hipStream_t stream)
{
    const float* x     = (const float*)d_in[0];
    const int*   Hp    = (const int*)d_in[1];
    const float* ln_g  = (const float*)d_in[2];
    const float* ln_b  = (const float*)d_in[3];
    const float* W_ih0 = (const float*)d_in[4];
    const float* W_hh0 = (const float*)d_in[5];
    const float* b_ih0 = (const float*)d_in[6];
    const float* b_hh0 = (const float*)d_in[7];
    const float* W_ih1 = (const float*)d_in[8];
    const float* W_hh1 = (const float*)d_in[9];
    const float* b_ih1 = (const float*)d_in[10];
    const float* b_hh1 = (const float*)d_in[11];
    const float* Wp    = (const float*)d_in[12];
    const float* bp    = (const float*)d_in[13];
    const float* prot  = (const float*)d_in[14];
    const float* Ws    = (const float*)d_in[15];
    const float* bs    = (const float*)d_in[16];
    const float* Wa    = (const float*)d_in[17];
    const float* ba    = (const float*)d_in[18];
    const float* Wf    = (const float*)d_in[19];
    const float* bf    = (const float*)d_in[20];
    float* out = (float*)d_out;
    (void)n_in; (void)out_size; (void)ws_size;

    const int T = 64, E = 64, K = 32;
    int N = in_sizes[0] / (T * 128);         // 4000
    size_t NT = (size_t)N * T;
    int NB = N / 8;                          // 500 gru/xg blocks

    const int ROWS_PER_BLK = 16;
    int P = (N + ROWS_PER_BLK - 1) / ROWS_PER_BLK;   // 250

    char* ws = (char*)d_ws;
    size_t off = 0;
    auto alloc = [&](size_t bytes) { char* p = ws + off; off += (bytes + 255) & ~(size_t)255; return p; };
    _Float16* xn  = (_Float16*)alloc(NT * 128 * 2);  // aliased as h1 (xn dead after k_xg L1)
    _Float16* h1  = xn;
    size_t nslot = (size_t)NB * 64 * 256;            // 2.048M slots
    _Float16* xgA = (_Float16*)alloc(nslot * 8 * 2); // 131 MB
    _Float16* xgB = (_Float16*)alloc(nslot * 4 * 2); //  65 MB
    float* e_s   = (float*)alloc((size_t)N * 128 * 4);
    float* e_p   = (float*)alloc((size_t)N * 128 * 4);
    float* e_r   = (float*)alloc((size_t)N * 128 * 4);
    float* beta  = (float*)alloc((size_t)N * K * 4);
    float* dn2   = (float*)alloc((size_t)N * 4);
    float* e_h   = (float*)alloc((size_t)N * 128 * 4);
    float* e_res = (float*)alloc((size_t)N * 128 * 4);
    float* part  = (float*)alloc((size_t)P * 2 * 32 * 128 * 4);
    float* m_buf = (float*)alloc((64 * 128 + 32 * 128) * 4);
    float* macc  = (float*)alloc((64 + 32) * 4);
    float* me   = m_buf;
    float* m2   = m_buf + 64 * 128;
    float* d_e  = macc;
    float* d_e2 = macc + 64;

    k_ln<<<(int)(NT / 16), 256, 0, stream>>>(x, ln_g, ln_b, xn);
    // layer 1
    k_xg<<<NB, 512, 0, stream>>>(xn, W_ih0, xgA, xgB);
    k_gru<<<NB, 512, 0, stream>>>(xgA, xgB, W_hh0, b_ih0, b_hh0, h1, nullptr);
    // layer 2
    k_xg<<<NB, 512, 0, stream>>>(h1, W_ih1, xgA, xgB);
    k_gru<<<NB, 512, 0, stream>>>(xgA, xgB, W_hh1, b_ih1, b_hh1, nullptr, e_s);

    hipMemsetAsync(macc, 0, (64 + 32) * 4, stream);
    // prior hconv: G = Hp^T @ e_s; me = (G/d_e) @ Wp^T ; apply
    k_edge_part<<<P, 256, 0, stream>>>(Hp, 1, e_s, part, d_e, E, N, ROWS_PER_BLK);
    k_finish_mm<<<E, 128, 0, stream>>>(part, d_e, Wp, nullptr, me, P, 2);
    k_hconv_apply<<<N / 8, 256, 0, stream>>>(Hp, 1, E, me, nullptr, 0, bp, e_s, e_p, e_r);

    // soft hconv
    k_mm32<<<N / 8, 256, 0, stream>>>(e_r, prot, beta, dn2);
    k_edge_part<<<P, 256, 0, stream>>>(beta, 0, e_r, part, d_e2, K, N, ROWS_PER_BLK);
    k_finish_mm<<<K, 128, 0, stream>>>(part, d_e2, Ws, bs, m2, P, 1);
    k_hconv_apply<<<N / 8, 256, 0, stream>>>(beta, 0, K, m2, dn2, 1, nullptr, e_r, e_h, e_res);

    k_tail<<<N / 16, 512, 0, stream>>>(e_res, Wa, ba, e_p, e_h, Wf, bf, out);
}

// Round 6
// 860.293 us; speedup vs baseline: 1.2271x; 1.2271x over previous
//
#include <hip/hip_runtime.h>
#include <hip/hip_fp16.h>

typedef float    f32x4 __attribute__((ext_vector_type(4)));
typedef _Float16 f16x8 __attribute__((ext_vector_type(8)));
typedef _Float16 f16x4 __attribute__((ext_vector_type(4)));

__device__ __forceinline__ float sigmoidf_(float x) { return 1.f / (1.f + __expf(-x)); }
__device__ __forceinline__ float tanhf_(float x) { float e = __expf(2.f * x); return 1.f - 2.f / (e + 1.f); }
__device__ __forceinline__ float lrelu_(float v) { return v > 0.f ? v : 0.01f * v; }

__device__ __forceinline__ f16x8 cvt8(const float* p) {
    const f32x4* q = (const f32x4*)p;
    f32x4 a = q[0], b = q[1];
    f16x8 v;
    v[0] = (_Float16)a[0]; v[1] = (_Float16)a[1]; v[2] = (_Float16)a[2]; v[3] = (_Float16)a[3];
    v[4] = (_Float16)b[0]; v[5] = (_Float16)b[1]; v[6] = (_Float16)b[2]; v[7] = (_Float16)b[3];
    return v;
}

// ---------------- LayerNorm + cast to f16, row-major [NT][128] ----------------
__global__ __launch_bounds__(256) void k_ln(const float* __restrict__ x,
                                            const float* __restrict__ g,
                                            const float* __restrict__ b,
                                            _Float16* __restrict__ xn)
{
    int tid = threadIdx.x;
    int r = tid >> 4, i = tid & 15;
    size_t row = (size_t)blockIdx.x * 16 + r;
    const f32x4* xp = (const f32x4*)(x + row * 128 + i * 8);
    f32x4 a0 = xp[0], a1 = xp[1];
    float v0=a0[0], v1=a0[1], v2=a0[2], v3=a0[3], v4=a1[0], v5=a1[1], v6=a1[2], v7=a1[3];
    float s  = v0+v1+v2+v3+v4+v5+v6+v7;
    float s2 = v0*v0+v1*v1+v2*v2+v3*v3+v4*v4+v5*v5+v6*v6+v7*v7;
#pragma unroll
    for (int m = 1; m <= 8; m <<= 1) { s += __shfl_xor(s, m); s2 += __shfl_xor(s2, m); }
    float mu  = s * (1.f / 128.f);
    float var = s2 * (1.f / 128.f) - mu * mu;
    float rs  = rsqrtf(var + 1e-5f);
    const f32x4* gp = (const f32x4*)(g + i * 8);
    const f32x4* bp = (const f32x4*)(b + i * 8);
    f32x4 g0 = gp[0], g1 = gp[1], bb0 = bp[0], bb1 = bp[1];
    f16x8 o;
    o[0] = (_Float16)((v0 - mu) * rs * g0[0] + bb0[0]);
    o[1] = (_Float16)((v1 - mu) * rs * g0[1] + bb0[1]);
    o[2] = (_Float16)((v2 - mu) * rs * g0[2] + bb0[2]);
    o[3] = (_Float16)((v3 - mu) * rs * g0[3] + bb0[3]);
    o[4] = (_Float16)((v4 - mu) * rs * g1[0] + bb1[0]);
    o[5] = (_Float16)((v5 - mu) * rs * g1[1] + bb1[1]);
    o[6] = (_Float16)((v6 - mu) * rs * g1[2] + bb1[2]);
    o[7] = (_Float16)((v7 - mu) * rs * g1[3] + bb1[7-4]);
    *(f16x8*)(xn + row * 128 + i * 8) = o;
}

// ---------------- xg = xin @ W_ih^T, stored PRE-PERMUTED for k_gru ----------------
// Block = 16 real batch rows, t-chunk of 32 (gridDim.y=2). Lane (w,ul,q) computes
// gate cols u=w*16+ul (+g*128) for C rows q*4+j (16 real rows). Store per lane:
//   slot = blk*64*512 + t*512 + w*64 + q*16 + ul
//   xgA[slot] = {r0..r3, z0..z3} (16B)   xgB[slot] = {n0..n3} (8B)
__global__ __launch_bounds__(512, 2) void k_xg(const _Float16* __restrict__ xin,
                                               const float* __restrict__ W,
                                               _Float16* __restrict__ xgA,
                                               _Float16* __restrict__ xgB)
{
    int tid = threadIdx.x;
    int w = tid >> 6, lane = tid & 63;
    int ul = lane & 15, q = lane >> 4;
    int u = w * 16 + ul;
    f16x8 wf[12];
#pragma unroll
    for (int g = 0; g < 3; ++g)
#pragma unroll
        for (int kt = 0; kt < 4; ++kt)
            wf[g * 4 + kt] = cvt8(W + (size_t)(u + g * 128) * 128 + kt * 32 + q * 8);
    int n0 = blockIdx.x * 16;
    int t0 = blockIdx.y * 32;
    const _Float16* xr = xin + ((size_t)(n0 + ul) * 64 + t0) * 128 + q * 8;
    size_t slotw = (size_t)blockIdx.x * 64 * 512 + (w * 64 + q * 16 + ul);
    const f32x4 zero4 = {0.f, 0.f, 0.f, 0.f};
    for (int t = t0; t < t0 + 32; ++t) {
        f16x8 xf[4];
#pragma unroll
        for (int kt = 0; kt < 4; ++kt) xf[kt] = *(const f16x8*)(xr + kt * 32);
        xr += 128;
        f32x4 ac[3];
#pragma unroll
        for (int g = 0; g < 3; ++g) ac[g] = zero4;
#pragma unroll
        for (int g = 0; g < 3; ++g)
#pragma unroll
            for (int kt = 0; kt < 4; ++kt)
                ac[g] = __builtin_amdgcn_mfma_f32_16x16x32_f16(xf[kt], wf[g * 4 + kt], ac[g], 0, 0, 0);
        size_t slot = slotw + (size_t)t * 512;
        f16x8 va; f16x4 vb;
#pragma unroll
        for (int j = 0; j < 4; ++j) {
            va[j]     = (_Float16)ac[0][j];
            va[4 + j] = (_Float16)ac[1][j];
            vb[j]     = (_Float16)ac[2][j];
        }
        *(f16x8*)(xgA + slot * 8) = va;
        *(f16x4*)(xgB + slot * 4) = vb;
    }
}

// ---------------- Recurrent GRU: 16 real rows/block, 250 blocks, 1 pass ----------
__global__ __launch_bounds__(512, 2) void k_gru(const _Float16* __restrict__ xgA,
                                                const _Float16* __restrict__ xgB,
                                                const float* __restrict__ W_hh,
                                                const float* __restrict__ b_ih,
                                                const float* __restrict__ b_hh,
                                                _Float16* __restrict__ hout,
                                                float* __restrict__ es)
{
    __shared__ __align__(16) _Float16 hbuf[2][16 * 136];
    int tid = threadIdx.x;
    int w = tid >> 6, lane = tid & 63;
    int ul = lane & 15, q = lane >> 4;
    int u = w * 16 + ul;
    int n0 = blockIdx.x * 16;

    f16x8 whh[12];
#pragma unroll
    for (int g = 0; g < 3; ++g)
#pragma unroll
        for (int kt = 0; kt < 4; ++kt)
            whh[g * 4 + kt] = cvt8(W_hh + (size_t)(u + g * 128) * 128 + kt * 32 + q * 8);
    float br = b_ih[u] + b_hh[u];
    float bz = b_ih[u + 128] + b_hh[u + 128];
    float bi2 = b_ih[u + 256], bh2 = b_hh[u + 256];

    size_t slot0 = (size_t)blockIdx.x * 64 * 512 + (w * 64 + q * 16 + ul);
    const f16x8* pA = (const f16x8*)xgA;
    const f16x4* pB = (const f16x4*)xgB;
    f16x8 curA = pA[slot0];
    f16x4 curB = pB[slot0];

    for (int idx = tid; idx < 16 * 136; idx += 512) hbuf[0][idx] = (_Float16)0.f;
    float hh[4] = {0.f, 0.f, 0.f, 0.f};
    __syncthreads();

    int p = 0;
    const f32x4 zero4 = {0.f, 0.f, 0.f, 0.f};
    for (int t = 0; t < 64; ++t) {
        size_t sn = slot0 + (size_t)((t < 63) ? (t + 1) : t) * 512;
        f16x8 nxtA = pA[sn];
        f16x4 nxtB = pB[sn];

        f16x8 hf[4];
        const _Float16* hb = &hbuf[p][ul * 136 + q * 8];
#pragma unroll
        for (int kt = 0; kt < 4; ++kt) hf[kt] = *(const f16x8*)(hb + kt * 32);

        f32x4 ah[3];
#pragma unroll
        for (int g = 0; g < 3; ++g) ah[g] = zero4;
#pragma unroll
        for (int g = 0; g < 3; ++g)
#pragma unroll
            for (int kt = 0; kt < 4; ++kt)
                ah[g] = __builtin_amdgcn_mfma_f32_16x16x32_f16(hf[kt], whh[g * 4 + kt], ah[g], 0, 0, 0);

        _Float16* wb = &hbuf[p ^ 1][0];
#pragma unroll
        for (int j = 0; j < 4; ++j) {
            float rr = sigmoidf_((float)curA[j] + ah[0][j] + br);
            float zz = sigmoidf_((float)curA[4 + j] + ah[1][j] + bz);
            float nn = tanhf_((float)curB[j] + bi2 + rr * (ah[2][j] + bh2));
            float hn = (1.f - zz) * nn + zz * hh[j];
            hh[j] = hn;
            wb[(q * 4 + j) * 136 + u] = (_Float16)hn;
        }
        __syncthreads();
        p ^= 1;
        if (hout != nullptr && tid < 256) {
            int r2 = tid >> 4, seg = tid & 15;
            f16x8 v = *(const f16x8*)&hbuf[p][r2 * 136 + seg * 8];
            *(f16x8*)(hout + ((size_t)(n0 + r2) * 64 + t) * 128 + seg * 8) = v;
        }
        curA = nxtA; curB = nxtB;
    }
    if (es != nullptr) {
#pragma unroll
        for (int j = 0; j < 4; ++j)
            es[(size_t)(n0 + q * 4 + j) * 128 + u] = hh[j];
    }
}

// ---------------- edge reduce, stage 1: G[j][c] partials = sum_n S[n][j]*X[n][c] ----
__global__ __launch_bounds__(256) void k_edge_part(const void* __restrict__ S, int isInt,
                                                   const float* __restrict__ X,
                                                   float* __restrict__ part,
                                                   float* __restrict__ d_e,
                                                   int E, int N, int rowsPerBlk)
{
    int tid = threadIdx.x;
    int pair = tid >> 7, c = tid & 127, lane = tid & 63;
    int JG = E >> 5;
    int jg, rOff, rStep;
    if (JG == 2) { jg = pair; rOff = 0; rStep = 1; }
    else         { jg = 0;    rOff = pair; rStep = 2; }
    int n0 = blockIdx.x * rowsPerBlk;
    int n1 = n0 + rowsPerBlk; if (n1 > N) n1 = N;
    const int* Si = (const int*)S; const float* Sf = (const float*)S;
    int js = jg * 32 + (lane & 31);

    float acc[32];
#pragma unroll
    for (int i = 0; i < 32; ++i) acc[i] = 0.f;
    float dcnt = 0.f;

    for (int n = n0 + rOff; n < n1; n += rStep) {
        float sval = isInt ? (float)Si[(size_t)n * E + js] : Sf[(size_t)n * E + js];
        float xc = X[(size_t)n * 128 + c];
        dcnt += sval;
        int sv = __float_as_int(sval);
#pragma unroll
        for (int jj = 0; jj < 32; ++jj) {
            float s = __int_as_float(__builtin_amdgcn_readlane(sv, jj));
            acc[jj] += s * xc;
        }
    }
    float* pp = part + ((size_t)(blockIdx.x * 2 + pair) * 32) * 128;
#pragma unroll
    for (int jj = 0; jj < 32; ++jj)
        pp[(size_t)jj * 128 + c] = acc[jj];
    int w = tid >> 6;
    if ((w & 1) == 0 && (lane & 32) == 0)
        atomicAdd(&d_e[jg * 32 + lane], dcnt);
}

// ---------------- stage 2: Gsum -> m[j] = (G[j]*scale_j) @ W^T + bias ----------------
__global__ __launch_bounds__(128) void k_finish_mm(const float* __restrict__ part,
                                                   const float* __restrict__ d_e,
                                                   const float* __restrict__ W,
                                                   const float* __restrict__ bias,
                                                   float* __restrict__ m, int P, int JG)
{
    __shared__ __align__(16) float Gj[128];
    int j = blockIdx.x, c = threadIdx.x;
    float acc = 0.f;
    if (JG == 2) {
        int pair = j >> 5, jj = j & 31;
        for (int b = 0; b < P; ++b)
            acc += part[((size_t)(b * 2 + pair) * 32 + jj) * 128 + c];
    } else {
        for (int b = 0; b < 2 * P; ++b)
            acc += part[((size_t)b * 32 + j) * 128 + c];
    }
    float d = d_e[j];
    float s = d > 0.f ? 1.f / d : 0.f;
    Gj[c] = acc * s;
    __syncthreads();
    const f32x4* Wr = (const f32x4*)(W + (size_t)c * 128);
    const f32x4* Gp = (const f32x4*)Gj;
    float dot = 0.f;
#pragma unroll 8
    for (int k4 = 0; k4 < 32; ++k4) {
        f32x4 wv = Wr[k4], gv = Gp[k4];
        dot += wv[0] * gv[0] + wv[1] * gv[1] + wv[2] * gv[2] + wv[3] * gv[3];
    }
    m[j * 128 + c] = dot + (bias ? bias[c] : 0.f);
}

// ---------------- hconv apply (+ optional fused beta=sigmoid(e_r@prot^T), dn2) ------
__global__ __launch_bounds__(256) void k_hconv_apply(const void* __restrict__ S, int isInt, int E,
                                                     const float* __restrict__ m,
                                                     const float* __restrict__ dn_pre, int sqrtMode,
                                                     const float* __restrict__ bias,
                                                     const float* __restrict__ base,
                                                     float* __restrict__ outMain,
                                                     float* __restrict__ outSub,
                                                     const float* __restrict__ prot,
                                                     float* __restrict__ betaOut,
                                                     float* __restrict__ dn2Out,
                                                     int doBeta)
{
    __shared__ float mls[64 * 128];
    __shared__ float er[8 * 128];
    __shared__ float pls[32 * 129];
    int tid = threadIdx.x;
    for (int idx = tid; idx < E * 128; idx += 256) mls[idx] = m[idx];
    if (doBeta)
        for (int idx = tid; idx < 32 * 128; idx += 256)
            pls[(idx >> 7) * 129 + (idx & 127)] = prot[idx];
    __syncthreads();
    int c = tid & 127, r = tid >> 7;
    for (int pass = 0; pass < 4; ++pass) {
        size_t n = (size_t)blockIdx.x * 8 + pass * 2 + r;
        float acc = 0.f, d = 0.f;
        if (isInt) {
            const int4* Sr = (const int4*)((const int*)S + n * E);
            for (int jg = 0; jg < E / 4; ++jg) {
                int4 s4 = Sr[jg];
                acc += (float)s4.x * mls[(jg * 4 + 0) * 128 + c]
                     + (float)s4.y * mls[(jg * 4 + 1) * 128 + c]
                     + (float)s4.z * mls[(jg * 4 + 2) * 128 + c]
                     + (float)s4.w * mls[(jg * 4 + 3) * 128 + c];
                d += (float)(s4.x + s4.y + s4.z + s4.w);
            }
        } else {
            const f32x4* Sr = (const f32x4*)((const float*)S + n * E);
            for (int jg = 0; jg < E / 4; ++jg) {
                f32x4 s4 = Sr[jg];
                acc += s4[0] * mls[(jg * 4 + 0) * 128 + c]
                     + s4[1] * mls[(jg * 4 + 1) * 128 + c]
                     + s4[2] * mls[(jg * 4 + 2) * 128 + c]
                     + s4[3] * mls[(jg * 4 + 3) * 128 + c];
                d += s4[0] + s4[1] + s4[2] + s4[3];
            }
        }
        if (dn_pre) d = dn_pre[n];
        float sc = d > 0.f ? (sqrtMode ? rsqrtf(d) : 1.f / d) : 0.f;
        float v = acc * sc + (bias ? bias[c] : 0.f);
        v = lrelu_(v);
        outMain[n * 128 + c] = v;
        if (outSub) {
            float sub = base[n * 128 + c] - v;
            outSub[n * 128 + c] = sub;
            if (doBeta) er[(pass * 2 + r) * 128 + c] = sub;
        }
    }
    if (doBeta) {
        __syncthreads();
        int o = tid & 31, r2 = tid >> 5;
        float acc2 = 0.f;
#pragma unroll 8
        for (int k = 0; k < 128; ++k)
            acc2 += er[r2 * 128 + k] * pls[o * 129 + k];
        float v2 = sigmoidf_(acc2);
        size_t n2 = (size_t)blockIdx.x * 8 + r2;
        betaOut[n2 * 32 + o] = v2;
        float sum = v2;
#pragma unroll
        for (int mm = 1; mm < 32; mm <<= 1) sum += __shfl_xor(sum, mm);
        if (o == 0) dn2Out[n2] = sum;
    }
}

// ---------------- tail: e_al = lrelu(e_res@Wa^T+ba); out = [e_p|e_h|e_al].Wf + bf ----
__global__ __launch_bounds__(512) void k_tail(const float* __restrict__ e_res,
                                              const float* __restrict__ Wa,
                                              const float* __restrict__ ba,
                                              const float* __restrict__ ep,
                                              const float* __restrict__ eh,
                                              const float* __restrict__ Wf,
                                              const float* __restrict__ bf,
                                              float* __restrict__ out)
{
    __shared__ __align__(16) _Float16 Wls[128 * 136];
    __shared__ float wfl[384];
    __shared__ float sred[8];
    int tid = threadIdx.x;
    for (int idx = tid; idx < 128 * 128; idx += 512) {
        int o = idx >> 7, k = idx & 127;
        Wls[o * 136 + k] = (_Float16)Wa[idx];
    }
    for (int idx = tid; idx < 384; idx += 512) wfl[idx] = Wf[idx];
    __syncthreads();
    int o = tid & 127, r = tid >> 7;
    for (int pass = 0; pass < 4; ++pass) {
        size_t n = (size_t)blockIdx.x * 16 + pass * 4 + r;
        const f32x4* Ap = (const f32x4*)(e_res + n * 128);
        float acc = ba[o];
#pragma unroll 4
        for (int k8 = 0; k8 < 16; ++k8) {
            f16x8 wv = *(const f16x8*)&Wls[o * 136 + k8 * 8];
            f32x4 a0 = Ap[k8 * 2], a1 = Ap[k8 * 2 + 1];
            acc += (float)wv[0] * a0[0] + (float)wv[1] * a0[1] + (float)wv[2] * a0[2] + (float)wv[3] * a0[3]
                 + (float)wv[4] * a1[0] + (float)wv[5] * a1[1] + (float)wv[6] * a1[2] + (float)wv[7] * a1[3];
        }
        float v = lrelu_(acc);
        float term = ep[n * 128 + o] * wfl[o] + eh[n * 128 + o] * wfl[128 + o] + v * wfl[256 + o];
#pragma unroll
        for (int m2 = 1; m2 < 64; m2 <<= 1) term += __shfl_xor(term, m2);
        int wv2 = tid >> 6;
        if ((tid & 63) == 0) sred[wv2] = term;
        __syncthreads();
        if (tid < 4) out[blockIdx.x * 16 + pass * 4 + tid] = sred[2 * tid] + sred[2 * tid + 1] + bf[0];
        __syncthreads();
    }
}

extern "C" void kernel_launch(void* const* d_in, const int* in_sizes, int n_in,
                              void* d_out, int out_size, void* d_ws, size_t ws_size,
                              hipStream_t stream)
{
    const float* x     = (const float*)d_in[0];
    const int*   Hp    = (const int*)d_in[1];
    const float* ln_g  = (const float*)d_in[2];
    const float* ln_b  = (const float*)d_in[3];
    const float* W_ih0 = (const float*)d_in[4];
    const float* W_hh0 = (const float*)d_in[5];
    const float* b_ih0 = (const float*)d_in[6];
    const float* b_hh0 = (const float*)d_in[7];
    const float* W_ih1 = (const float*)d_in[8];
    const float* W_hh1 = (const float*)d_in[9];
    const float* b_ih1 = (const float*)d_in[10];
    const float* b_hh1 = (const float*)d_in[11];
    const float* Wp    = (const float*)d_in[12];
    const float* bp    = (const float*)d_in[13];
    const float* prot  = (const float*)d_in[14];
    const float* Ws    = (const float*)d_in[15];
    const float* bs    = (const float*)d_in[16];
    const float* Wa    = (const float*)d_in[17];
    const float* ba    = (const float*)d_in[18];
    const float* Wf    = (const float*)d_in[19];
    const float* bf    = (const float*)d_in[20];
    float* out = (float*)d_out;
    (void)n_in; (void)out_size; (void)ws_size;

    const int T = 64, E = 64, K = 32;
    int N = in_sizes[0] / (T * 128);         // 4000
    size_t NT = (size_t)N * T;
    int NB = N / 16;                         // 250 gru/xg blocks

    const int ROWS_PER_BLK = 16;
    int P = (N + ROWS_PER_BLK - 1) / ROWS_PER_BLK;   // 250

    char* ws = (char*)d_ws;
    size_t off = 0;
    auto alloc = [&](size_t bytes) { char* p = ws + off; off += (bytes + 255) & ~(size_t)255; return p; };
    _Float16* xn  = (_Float16*)alloc(NT * 128 * 2);  // aliased as h1 (xn dead after k_xg L1)
    _Float16* h1  = xn;
    size_t nslot = (size_t)NB * 64 * 512;            // 8.192M slots
    _Float16* xgA = (_Float16*)alloc(nslot * 8 * 2); // 131 MB
    _Float16* xgB = (_Float16*)alloc(nslot * 4 * 2); //  65 MB
    float* e_s   = (float*)alloc((size_t)N * 128 * 4);
    float* e_p   = (float*)alloc((size_t)N * 128 * 4);
    float* e_r   = (float*)alloc((size_t)N * 128 * 4);
    float* beta  = (float*)alloc((size_t)N * K * 4);
    float* dn2   = (float*)alloc((size_t)N * 4);
    float* e_h   = (float*)alloc((size_t)N * 128 * 4);
    float* e_res = (float*)alloc((size_t)N * 128 * 4);
    float* part  = (float*)alloc((size_t)P * 2 * 32 * 128 * 4);
    float* m_buf = (float*)alloc((64 * 128 + 32 * 128) * 4);
    float* macc  = (float*)alloc((64 + 32) * 4);
    float* me   = m_buf;
    float* m2   = m_buf + 64 * 128;
    float* d_e  = macc;
    float* d_e2 = macc + 64;

    k_ln<<<(int)(NT / 16), 256, 0, stream>>>(x, ln_g, ln_b, xn);
    // layer 1
    k_xg<<<dim3(NB, 2), 512, 0, stream>>>(xn, W_ih0, xgA, xgB);
    k_gru<<<NB, 512, 0, stream>>>(xgA, xgB, W_hh0, b_ih0, b_hh0, h1, nullptr);
    // layer 2
    k_xg<<<dim3(NB, 2), 512, 0, stream>>>(h1, W_ih1, xgA, xgB);
    k_gru<<<NB, 512, 0, stream>>>(xgA, xgB, W_hh1, b_ih1, b_hh1, nullptr, e_s);

    hipMemsetAsync(macc, 0, (64 + 32) * 4, stream);
    // prior hconv: G = Hp^T @ e_s; me = (G/d_e) @ Wp^T ; apply (+ fused beta/dn2)
    k_edge_part<<<P, 256, 0, stream>>>(Hp, 1, e_s, part, d_e, E, N, ROWS_PER_BLK);
    k_finish_mm<<<E, 128, 0, stream>>>(part, d_e, Wp, nullptr, me, P, 2);
    k_hconv_apply<<<N / 8, 256, 0, stream>>>(Hp, 1, E, me, nullptr, 0, bp, e_s, e_p, e_r,
                                             prot, beta, dn2, 1);

    // soft hconv
    k_edge_part<<<P, 256, 0, stream>>>(beta, 0, e_r, part, d_e2, K, N, ROWS_PER_BLK);
    k_finish_mm<<<K, 128, 0, stream>>>(part, d_e2, Ws, bs, m2, P, 1);
    k_hconv_apply<<<N / 8, 256, 0, stream>>>(beta, 0, K, m2, dn2, 1, nullptr, e_r, e_h, e_res,
                                             nullptr, nullptr, nullptr, 0);

    k_tail<<<N / 16, 512, 0, stream>>>(e_res, Wa, ba, e_p, e_h, Wf, bf, out);
}